// Round 9
// baseline (421.949 us; speedup 1.0000x reference)
//
#include <hip/hip_runtime.h>

// ---------------- problem config ----------------
constexpr int CB = 4, CN = 4096, CD = 1024, CH = 16, CDH = 64, CGH = 256, CFREQ = 2049, CBH = 64;

// ---------------- workspace layout (float offsets) ----------------
constexpr size_t OFF_XSUM = 0;                                   // 4096
constexpr size_t OFF_HG   = 4096;
constexpr size_t OFF_HW   = OFF_HG + (size_t)CBH * CGH;
constexpr size_t OFF_GATE = OFF_HW + (size_t)CBH * CGH;
constexpr size_t OFF_S    = OFF_GATE + (size_t)CBH * 2 * CFREQ;
constexpr size_t OFF_CA   = OFF_S + (size_t)CBH * CN;
constexpr size_t OFF_CD   = OFF_CA + (size_t)CBH * (CN / 2);
constexpr size_t OFF_TW   = OFF_CD + (size_t)CBH * (CN / 2);     // 4096 float2 = 8192 floats
constexpr size_t OFF_VCOL = OFF_TW + 8192;                       // fp32 [b][d][n]
constexpr size_t OFF_XHI  = OFF_VCOL + (size_t)CB * CD * CN;     // bf16 planes
constexpr size_t OFF_XLO  = OFF_XHI + (size_t)CB * CN * CD / 2;
constexpr size_t OFF_WVHI = OFF_XLO + (size_t)CB * CN * CD / 2;
constexpr size_t OFF_WVLO = OFF_WVHI + (size_t)CD * CD / 2;
constexpr size_t OFF_WOHI = OFF_WVLO + (size_t)CD * CD / 2;
constexpr size_t OFF_WOLO = OFF_WOHI + (size_t)CD * CD / 2;
// V2 planes alias X planes (X dead after GEMM1).
// g~rev table (64 x 4096 float2 = 524288 floats) aliases WVHI (dead after GEMM1).

typedef __bf16 bf16x8 __attribute__((ext_vector_type(8)));
typedef __bf16 bf16x4 __attribute__((ext_vector_type(4)));
typedef float  f32x4  __attribute__((ext_vector_type(4)));
typedef float  f32x16 __attribute__((ext_vector_type(16)));

__device__ __forceinline__ float silu_f(float x) { return x / (1.0f + expf(-x)); }

__device__ __forceinline__ void gload16(const void* g, void* l) {
    __builtin_amdgcn_global_load_lds(
        reinterpret_cast<const __attribute__((address_space(1))) unsigned int*>(
            reinterpret_cast<uintptr_t>(g)),
        reinterpret_cast<__attribute__((address_space(3))) unsigned int*>(
            reinterpret_cast<uintptr_t>(l)),
        16, 0, 0);
}

// complex helpers
__device__ __forceinline__ float2 cadd(float2 a, float2 b) { return make_float2(a.x + b.x, a.y + b.y); }
__device__ __forceinline__ float2 csub(float2 a, float2 b) { return make_float2(a.x - b.x, a.y - b.y); }
__device__ __forceinline__ float2 cmul(float2 a, float2 b) { return make_float2(a.x * b.x - a.y * b.y, a.x * b.y + a.y * b.x); }
__device__ __forceinline__ float2 cmulc(float2 a, float2 b) { return make_float2(a.x * b.x + a.y * b.y, a.y * b.x - a.x * b.y); } // a*conj(b)
__device__ __forceinline__ float2 mulni(float2 a) { return make_float2(a.y, -a.x); }  // a * (-i)
__device__ __forceinline__ float2 mulpi(float2 a) { return make_float2(-a.y, a.x); }  // a * (+i)

// padded LDS slot: uniform bank residues (4 lanes/residue = b64 minimum) for all stage strides
__device__ __forceinline__ int P(int r) { return r + (r >> 3); }

// base-8 digit reversal of 12-bit index (involution)
__device__ __forceinline__ int drev8(int k) {
    return ((k & 7) << 9) | (((k >> 3) & 7) << 6) | (((k >> 6) & 7) << 3) | ((k >> 9) & 7);
}

// 8-pt DFT, forward (w = e^{-2pi i/8})
__device__ __forceinline__ void dft8_fwd(const float2 a[8], float2 A[8]) {
    float2 t0 = cadd(a[0], a[4]), t1 = csub(a[0], a[4]);
    float2 t2 = cadd(a[2], a[6]), t3 = mulni(csub(a[2], a[6]));
    float2 t4 = cadd(a[1], a[5]), t5 = csub(a[1], a[5]);
    float2 t6 = cadd(a[3], a[7]), t7 = mulni(csub(a[3], a[7]));
    float2 u0 = cadd(t0, t2), u1 = csub(t0, t2);
    float2 u2 = cadd(t1, t3), u3 = csub(t1, t3);
    float2 u4 = cadd(t4, t6), u5 = mulni(csub(t4, t6));
    float2 u6 = cadd(t5, t7), u7 = csub(t5, t7);
    const float s = 0.70710678118654752f;
    float2 w6 = make_float2(s * (u6.x + u6.y), s * (u6.y - u6.x));
    float2 w7 = make_float2(s * (u7.y - u7.x), -s * (u7.x + u7.y));
    A[0] = cadd(u0, u4); A[4] = csub(u0, u4);
    A[2] = cadd(u1, u5); A[6] = csub(u1, u5);
    A[1] = cadd(u2, w6); A[5] = csub(u2, w6);
    A[3] = cadd(u3, w7); A[7] = csub(u3, w7);
}

// 8-pt DFT, inverse (w = e^{+2pi i/8})
__device__ __forceinline__ void dft8_inv(const float2 a[8], float2 A[8]) {
    float2 t0 = cadd(a[0], a[4]), t1 = csub(a[0], a[4]);
    float2 t2 = cadd(a[2], a[6]), t3 = mulpi(csub(a[2], a[6]));
    float2 t4 = cadd(a[1], a[5]), t5 = csub(a[1], a[5]);
    float2 t6 = cadd(a[3], a[7]), t7 = mulpi(csub(a[3], a[7]));
    float2 u0 = cadd(t0, t2), u1 = csub(t0, t2);
    float2 u2 = cadd(t1, t3), u3 = csub(t1, t3);
    float2 u4 = cadd(t4, t6), u5 = mulpi(csub(t4, t6));
    float2 u6 = cadd(t5, t7), u7 = csub(t5, t7);
    const float s = 0.70710678118654752f;
    float2 w6 = make_float2(s * (u6.x - u6.y), s * (u6.x + u6.y));
    float2 w7 = make_float2(-s * (u7.x + u7.y), s * (u7.x - u7.y));
    A[0] = cadd(u0, u4); A[4] = csub(u0, u4);
    A[2] = cadd(u1, u5); A[6] = csub(u1, u5);
    A[1] = cadd(u2, w6); A[5] = csub(u2, w6);
    A[3] = cadd(u3, w7); A[7] = csub(u3, w7);
}

template <int M>
__device__ __forceinline__ void fwd_stage(float2* buf, const float2* __restrict__ tw, int t) {
    int j = t & (M - 1);
    int i0 = ((t & ~(M - 1)) << 3) + j;
    constexpr int TS = 512 / M;
    float2 a[8], A[8];
#pragma unroll
    for (int c = 0; c < 8; ++c) a[c] = buf[P(i0 + c * M)];
    dft8_fwd(a, A);
#pragma unroll
    for (int p = 0; p < 8; ++p) {
        float2 v = (M > 1 && p) ? cmul(A[p], tw[j * p * TS]) : A[p];
        buf[P(i0 + p * M)] = v;
    }
}

template <int M>
__device__ __forceinline__ void inv_stage(float2* buf, const float2* __restrict__ tw, int t) {
    int j = t & (M - 1);
    int i0 = ((t & ~(M - 1)) << 3) + j;
    constexpr int TS = 512 / M;
    float2 a[8], A[8];
#pragma unroll
    for (int c = 0; c < 8; ++c) {
        float2 v = buf[P(i0 + c * M)];
        a[c] = (M > 1 && c) ? cmulc(v, tw[j * c * TS]) : v;
    }
    dft8_inv(a, A);
#pragma unroll
    for (int p = 0; p < 8; ++p) buf[P(i0 + p * M)] = A[p];
}

// ---------------- twiddle table ----------------
__global__ void k_tw(float* twf) {
    int i = blockIdx.x * 256 + threadIdx.x;
    if (i < 4096) {
        double ang = -2.0 * 3.14159265358979323846 * (double)i / 4096.0;
        twf[2 * i]     = (float)cos(ang);
        twf[2 * i + 1] = (float)sin(ang);
    }
}

// ---------------- g~ in digit-reversed order: grev[bh][r] = g~(drev8(r)) ----------------
// g~(k) = g(k) for k<=2048, conj(g(4096-k)) for k>2048. (Gate collapses to pointwise
// multiply of the packed spectrum: W[k] = g~(k) * Z[k] -- algebra in journal.)
__global__ __launch_bounds__(256) void k_grev(const float* __restrict__ gateB,
                                              float2* __restrict__ grev) {
    int bh = blockIdx.y;
    int r = blockIdx.x * 256 + threadIdx.x;   // 0..4095
    int k = drev8(r);
    const float2* g2 = (const float2*)gateB + (size_t)bh * CFREQ;
    float2 g;
    if (k <= 2048) g = g2[k];
    else { float2 gg = g2[4096 - k]; g = make_float2(gg.x, -gg.y); }
    grev[(size_t)bh * 4096 + r] = g;
}

// ---------------- column sums of x over N, fused with hi/lo bf16 split ----------------
__global__ __launch_bounds__(256) void k_meansplit(const float* __restrict__ X, float* __restrict__ xsum,
                                                   __bf16* __restrict__ hi, __bf16* __restrict__ lo) {
    int b = blockIdx.y;
    int c = blockIdx.x;
    int t = threadIdx.x;
    int half = t >> 7;
    int col = (t & 127) * 8;
    size_t base = (size_t)b * CN * CD + ((size_t)c * 64 + half * 32) * CD + col;
    float acc[8];
#pragma unroll
    for (int j = 0; j < 8; ++j) acc[j] = 0.f;
    for (int n = 0; n < 32; ++n) {
        size_t o = base + (size_t)n * CD;
        float4 v0 = *(const float4*)(X + o);
        float4 v1 = *(const float4*)(X + o + 4);
        float vv[8] = {v0.x, v0.y, v0.z, v0.w, v1.x, v1.y, v1.z, v1.w};
        bf16x8 hv, lv;
#pragma unroll
        for (int j = 0; j < 8; ++j) {
            acc[j] += vv[j];
            __bf16 h = (__bf16)vv[j];
            hv[j] = h;
            lv[j] = (__bf16)(vv[j] - (float)h);
        }
        *(bf16x8*)&hi[o] = hv;
        *(bf16x8*)&lo[o] = lv;
    }
#pragma unroll
    for (int j = 0; j < 8; ++j) atomicAdd(&xsum[b * CD + col + j], acc[j]);
}

// ---------------- bar = LN(mean_n q) ; hidden = silu(bar @ Wup.T) ----------------
__global__ __launch_bounds__(256) void k_barhidden(const float* __restrict__ xsum,
                                                   const float* __restrict__ Wq,
                                                   const float* __restrict__ ln_g,
                                                   const float* __restrict__ ln_b,
                                                   const float* __restrict__ Wgup,
                                                   const float* __restrict__ Wwup,
                                                   float* __restrict__ hg, float* __restrict__ hw) {
    int bh = blockIdx.x;
    int b = bh >> 4, h = bh & 15;
    int t = threadIdx.x;
    __shared__ float part[256];
    __shared__ float bar_s[64];
    int dh = t >> 2, seg = t & 3;
    const float* wrow = Wq + (size_t)(h * 64 + dh) * CD + seg * 256;
    const float* xs = xsum + b * CD + seg * 256;
    float acc = 0.f;
    for (int i = 0; i < 256; i += 4) {
        float4 w4 = *(const float4*)(wrow + i);
        float4 x4 = *(const float4*)(xs + i);
        acc += w4.x * x4.x + w4.y * x4.y + w4.z * x4.z + w4.w * x4.w;
    }
    part[t] = acc;
    __syncthreads();
    if (t < 64) {
        float q = (part[4 * t] + part[4 * t + 1] + part[4 * t + 2] + part[4 * t + 3]) * (1.0f / 4096.0f);
        float mu = q;
        for (int o = 32; o >= 1; o >>= 1) mu += __shfl_xor(mu, o, 64);
        mu *= (1.0f / 64.0f);
        float dev = q - mu;
        float vv = dev * dev;
        for (int o = 32; o >= 1; o >>= 1) vv += __shfl_xor(vv, o, 64);
        vv *= (1.0f / 64.0f);
        bar_s[t] = dev / sqrtf(vv + 1e-6f) * ln_g[t] + ln_b[t];
    }
    __syncthreads();
    const float* gup = Wgup + (size_t)t * CDH;
    const float* wup = Wwup + (size_t)t * CDH;
    float ag = 0.f, aw = 0.f;
    for (int i = 0; i < CDH; i += 4) {
        float4 bb = *(const float4*)(&bar_s[i]);
        float4 g4 = *(const float4*)(gup + i);
        float4 w4 = *(const float4*)(wup + i);
        ag += g4.x * bb.x + g4.y * bb.y + g4.z * bb.z + g4.w * bb.w;
        aw += w4.x * bb.x + w4.y * bb.y + w4.z * bb.z + w4.w * bb.w;
    }
    hg[bh * CGH + t] = silu_f(ag);
    hw[bh * CGH + t] = silu_f(aw);
}

// ---------------- gr / s GEMVs ----------------
__global__ __launch_bounds__(256) void k_gategemv(const float* __restrict__ Wgdn,
                                                  const float* __restrict__ Wwdn,
                                                  const float* __restrict__ hg,
                                                  const float* __restrict__ hw,
                                                  float* __restrict__ gate, float* __restrict__ sbuf) {
    int z = blockIdx.z;
    const float* Wd = z ? Wwdn : Wgdn;
    const float* hid = z ? hw : hg;
    float* out = z ? sbuf : gate;
    int Kout = z ? CN : 2 * CFREQ;
    int bh0 = blockIdx.y * 8;
    int t = threadIdx.x;
    int k = blockIdx.x * 256 + t;
    __shared__ float Lh[8][256];
    for (int g = 0; g < 8; ++g) Lh[g][t] = hid[(size_t)(bh0 + g) * CGH + t];
    __syncthreads();
    if (k >= Kout) return;
    float accv[8] = {0.f, 0.f, 0.f, 0.f, 0.f, 0.f, 0.f, 0.f};
    const float* wrow = Wd + (size_t)k * CGH;
    for (int j4 = 0; j4 < 64; ++j4) {
        float4 wv = *(const float4*)(wrow + 4 * j4);
#pragma unroll
        for (int g = 0; g < 8; ++g) {
            accv[g] += wv.x * Lh[g][4 * j4] + wv.y * Lh[g][4 * j4 + 1] +
                       wv.z * Lh[g][4 * j4 + 2] + wv.w * Lh[g][4 * j4 + 3];
        }
    }
    for (int g = 0; g < 8; ++g) out[(size_t)(bh0 + g) * Kout + k] = accv[g];
}

// ---------------- mixing coefficients ----------------
__global__ __launch_bounds__(256) void k_coef(const float* __restrict__ sbuf,
                                              float* __restrict__ ca, float* __restrict__ cd) {
    int bh = blockIdx.y;
    int i = blockIdx.x * 256 + threadIdx.x;
    float s0 = sbuf[(size_t)bh * CN + i];
    float s1 = sbuf[(size_t)bh * CN + 2048 + i];
    ca[(size_t)bh * 2048 + i] = 1.0f + 0.5f * (s0 + s1);
    cd[(size_t)bh * 2048 + i] = 0.5f * (s0 - s1);
}

// ---------------- fp32 -> (hi,lo) bf16 split (weights) ----------------
__global__ __launch_bounds__(256) void k_split(const float* __restrict__ src,
                                               __bf16* __restrict__ hi, __bf16* __restrict__ lo,
                                               int n4) {
    int i = blockIdx.x * 256 + threadIdx.x;
    int stride = gridDim.x * 256;
    for (; i < n4; i += stride) {
        float4 v = ((const float4*)src)[i];
        __bf16 h0 = (__bf16)v.x, h1 = (__bf16)v.y, h2 = (__bf16)v.z, h3 = (__bf16)v.w;
        bf16x4 hv = {h0, h1, h2, h3};
        bf16x4 lv = {(__bf16)(v.x - (float)h0), (__bf16)(v.y - (float)h1),
                     (__bf16)(v.z - (float)h2), (__bf16)(v.w - (float)h3)};
        *(bf16x4*)&hi[4 * (size_t)i] = hv;
        *(bf16x4*)&lo[4 * (size_t)i] = lv;
    }
}

// ---------------- transpose + split: Vcol fp32 [b][d][n] -> V2 planes [b*n][d] ----------------
__global__ __launch_bounds__(256) void k_tsplit(const float* __restrict__ Vcol,
                                                __bf16* __restrict__ hi, __bf16* __restrict__ lo) {
    __shared__ float tile[32][33];
    int bx = blockIdx.x;
    int by = blockIdx.y;
    int b  = blockIdx.z;
    int t = threadIdx.x;
    int d = t >> 3, n4 = (t & 7) * 4;
    const float* src = Vcol + ((size_t)b * CD + by * 32 + d) * CN + bx * 32 + n4;
    float4 v = *(const float4*)src;
    tile[d][n4] = v.x; tile[d][n4 + 1] = v.y; tile[d][n4 + 2] = v.z; tile[d][n4 + 3] = v.w;
    __syncthreads();
    int n = t >> 3, d4 = (t & 7) * 4;
    size_t o = ((size_t)b * CN + bx * 32 + n) * CD + by * 32 + d4;
    float x0 = tile[d4][n], x1 = tile[d4 + 1][n], x2 = tile[d4 + 2][n], x3 = tile[d4 + 3][n];
    __bf16 h0 = (__bf16)x0, h1 = (__bf16)x1, h2 = (__bf16)x2, h3 = (__bf16)x3;
    bf16x4 hv = {h0, h1, h2, h3};
    bf16x4 lv = {(__bf16)(x0 - (float)h0), (__bf16)(x1 - (float)h1),
                 (__bf16)(x2 - (float)h2), (__bf16)(x3 - (float)h3)};
    *(bf16x4*)&hi[o] = hv;
    *(bf16x4*)&lo[o] = lv;
}

// ---------------- split-bf16 MFMA GEMM: 256x256 tile, 8 waves, 4-phase schedule ----------------
template <int TRANS>
__global__ __launch_bounds__(512, 2) void k_mfma_gemm(const __bf16* __restrict__ Ahi,
                                                      const __bf16* __restrict__ Alo,
                                                      const __bf16* __restrict__ Bhi,
                                                      const __bf16* __restrict__ Blo,
                                                      float* __restrict__ C) {
    __shared__ __align__(16) __bf16 lds[2][4][256 * 32];   // 128 KB
    int t = threadIdx.x;
    int l = t & 63, w = t >> 6;          // 8 waves
    int wm = w >> 2, wn = w & 3;         // 2m x 4n
    int hw = blockIdx.x;
    int xcd = hw & 7, slot = hw >> 3;    // 32 blocks per XCD: 8m x 4n
    int m0 = (xcd * 8 + (slot >> 2)) * 256;
    int n0 = (slot & 3) * 256;

    int pl = w >> 1;
    const __bf16* gsrc = (pl == 0) ? Ahi : (pl == 1) ? Alo : (pl == 2) ? Bhi : Blo;
    int gr0 = (pl < 2) ? m0 : n0;
    unsigned o[8];
    int rl0[8];
#pragma unroll
    for (int i = 0; i < 8; ++i) {
        int rl = (w & 1) * 128 + i * 16 + (l >> 2);
        unsigned sq = (unsigned)((l & 3) ^ ((rl >> 2) & 3));
        o[i] = (unsigned)(gr0 + rl) * 1024u + sq * 8u;
        rl0[i] = (w & 1) * 128 + i * 16;
    }

    f32x16 acc[4][2];
#pragma unroll
    for (int mi = 0; mi < 4; ++mi)
#pragma unroll
        for (int ni = 0; ni < 2; ++ni)
#pragma unroll
            for (int q = 0; q < 16; ++q) acc[mi][ni][q] = 0.f;

#pragma unroll
    for (int i = 0; i < 8; ++i)
        gload16(gsrc + (size_t)o[i], &lds[0][pl][rl0[i] * 32]);
    __syncthreads();

#pragma unroll 1
    for (int t32 = 0; t32 < 32; ++t32) {
        int cur = t32 & 1;
        size_t koff = (size_t)(t32 + 1) * 32;
        bool pf = (t32 + 1) < 32;
        bf16x8 bfr[2][2][2];
#pragma unroll
        for (int p = 0; p < 4; ++p) {
            if (pf) {
                gload16(gsrc + ((size_t)o[2 * p] + koff), &lds[cur ^ 1][pl][rl0[2 * p] * 32]);
                gload16(gsrc + ((size_t)o[2 * p + 1] + koff), &lds[cur ^ 1][pl][rl0[2 * p + 1] * 32]);
            }
            bf16x8 afr[2][2];
            int arow = wm * 128 + p * 32 + (l & 31);
            int akey = (arow >> 2) & 3;
#pragma unroll
            for (int s = 0; s < 2; ++s) {
                int sl = ((l >> 5) + 2 * s) ^ akey;
                afr[s][0] = *(const bf16x8*)&lds[cur][0][arow * 32 + sl * 8];
                afr[s][1] = *(const bf16x8*)&lds[cur][1][arow * 32 + sl * 8];
            }
            if (p == 0) {
#pragma unroll
                for (int ni = 0; ni < 2; ++ni) {
                    int bcol = wn * 64 + ni * 32 + (l & 31);
                    int bkey = (bcol >> 2) & 3;
#pragma unroll
                    for (int s = 0; s < 2; ++s) {
                        int sl = ((l >> 5) + 2 * s) ^ bkey;
                        bfr[ni][s][0] = *(const bf16x8*)&lds[cur][2][bcol * 32 + sl * 8];
                        bfr[ni][s][1] = *(const bf16x8*)&lds[cur][3][bcol * 32 + sl * 8];
                    }
                }
            }
            __builtin_amdgcn_s_barrier();
            __builtin_amdgcn_s_setprio(1);
#pragma unroll
            for (int ni = 0; ni < 2; ++ni)
#pragma unroll
                for (int s = 0; s < 2; ++s) {
                    acc[p][ni] = __builtin_amdgcn_mfma_f32_32x32x16_bf16(afr[s][0], bfr[ni][s][0], acc[p][ni], 0, 0, 0);
                    acc[p][ni] = __builtin_amdgcn_mfma_f32_32x32x16_bf16(afr[s][0], bfr[ni][s][1], acc[p][ni], 0, 0, 0);
                    acc[p][ni] = __builtin_amdgcn_mfma_f32_32x32x16_bf16(afr[s][1], bfr[ni][s][0], acc[p][ni], 0, 0, 0);
                }
            __builtin_amdgcn_s_setprio(0);
            __builtin_amdgcn_s_barrier();
        }
        __syncthreads();
    }

    if (TRANS) {
        int b = m0 >> 12;
        int tokb = (m0 & 4095) + wm * 128;
#pragma unroll
        for (int mi = 0; mi < 4; ++mi)
#pragma unroll
            for (int ni = 0; ni < 2; ++ni) {
                int dcol = n0 + wn * 64 + ni * 32 + (l & 31);
                float* base = C + ((size_t)(b * CD + dcol)) * CN;
#pragma unroll
                for (int q = 0; q < 4; ++q) {
                    int tok = tokb + mi * 32 + 8 * q + 4 * (l >> 5);
                    f32x4 v = {acc[mi][ni][4 * q], acc[mi][ni][4 * q + 1],
                               acc[mi][ni][4 * q + 2], acc[mi][ni][4 * q + 3]};
                    *(f32x4*)&base[tok] = v;
                }
            }
    } else {
#pragma unroll
        for (int mi = 0; mi < 4; ++mi)
#pragma unroll
            for (int ni = 0; ni < 2; ++ni) {
                int cc = n0 + wn * 64 + ni * 32 + (l & 31);
#pragma unroll
                for (int q = 0; q < 4; ++q) {
                    int r0 = m0 + wm * 128 + mi * 32 + 8 * q + 4 * (l >> 5);
#pragma unroll
                    for (int j = 0; j < 4; ++j)
                        C[(size_t)(r0 + j) * CD + cc] = acc[mi][ni][4 * q + j];
                }
            }
    }
}

// ---------------- FFT chain: radix-8 in registers, fused pointwise gate, 6 barriers ----------------
__global__ __launch_bounds__(512, 8) void k_fft(float* __restrict__ Vcol,
                                                const float2* __restrict__ grevB,
                                                const float* __restrict__ caB,
                                                const float* __restrict__ cdB,
                                                const float2* __restrict__ tw) {
    __shared__ float2 buf[4608];   // 4096 + pad(r>>3), 36 KB
    int blk = blockIdx.x;
    int bh = blk >> 5, pr = blk & 31;
    int t = threadIdx.x;
    float* colA = Vcol + (size_t)(bh * 64 + pr * 2) * CN;
    float* colB = colA + CN;

    // fwd stage M=512: global -> regs -> dft8 -> twiddle -> LDS
    {
        float2 a[8], A[8];
#pragma unroll
        for (int c = 0; c < 8; ++c) {
            int n = t + 512 * c;
            a[c] = make_float2(colA[n], colB[n]);
        }
        dft8_fwd(a, A);
#pragma unroll
        for (int p = 0; p < 8; ++p) {
            float2 v = p ? cmul(A[p], tw[t * p]) : A[p];
            buf[P(t + 512 * p)] = v;
        }
    }
    __syncthreads();
    fwd_stage<64>(buf, tw, t);  __syncthreads();
    fwd_stage<8>(buf, tw, t);   __syncthreads();

    // fused: fwd stage M=1 + pointwise gate (W[r] = g~rev[r] * Z[r]) + inv stage M=1.
    // i0 = 8t: slot residue 9t+p mod 16 -> conflict-free; grev reads coalesced.
    {
        const float2* gr = grevB + (size_t)bh * 4096 + (t << 3);
        int i0 = t << 3;
        float2 a[8], A[8];
#pragma unroll
        for (int c = 0; c < 8; ++c) a[c] = buf[P(i0 + c)];
        dft8_fwd(a, A);
#pragma unroll
        for (int p = 0; p < 8; ++p) A[p] = cmul(gr[p], A[p]);
        dft8_inv(A, a);
#pragma unroll
        for (int p = 0; p < 8; ++p) buf[P(i0 + p)] = a[p];
    }
    __syncthreads();

    inv_stage<8>(buf, tw, t);   __syncthreads();
    inv_stage<64>(buf, tw, t);  __syncthreads();

    // inv stage M=512 in registers + shfl-pair epilogue
    {
        float2 a[8], A[8];
#pragma unroll
        for (int c = 0; c < 8; ++c) {
            float2 v = buf[P(t + 512 * c)];
            a[c] = c ? cmulc(v, tw[t * c]) : v;
        }
        dft8_inv(a, A);
        const float scale = 1.0f / 4096.0f;
        const float* ca = caB + (size_t)bh * 2048;
        const float* cd = cdB + (size_t)bh * 2048;
#pragma unroll
        for (int p = 0; p < 8; ++p) {
            int n = t + 512 * p;
            int i = n >> 1;
            float A_ = ca[i] * scale, D_ = cd[i] * scale;
            float ox = __shfl_xor(A[p].x, 1, 64);
            float oy = __shfl_xor(A[p].y, 1, 64);
            colA[n] = A_ * A[p].x + D_ * ox;
            colB[n] = A_ * A[p].y + D_ * oy;
        }
    }
}

// ---------------- launch ----------------
extern "C" void kernel_launch(void* const* d_in, const int* in_sizes, int n_in,
                              void* d_out, int out_size, void* d_ws, size_t ws_size,
                              hipStream_t stream) {
    const float* x    = (const float*)d_in[0];
    const float* Wq   = (const float*)d_in[1];
    const float* Wv   = (const float*)d_in[2];
    const float* Wo   = (const float*)d_in[3];
    const float* ln_g = (const float*)d_in[4];
    const float* ln_b = (const float*)d_in[5];
    const float* Wgup = (const float*)d_in[6];
    const float* Wgdn = (const float*)d_in[7];
    const float* Wwup = (const float*)d_in[8];
    const float* Wwdn = (const float*)d_in[9];
    float* ws  = (float*)d_ws;
    float* out = (float*)d_out;

    __bf16* xhi  = (__bf16*)(ws + OFF_XHI);
    __bf16* xlo  = (__bf16*)(ws + OFF_XLO);
    __bf16* wvhi = (__bf16*)(ws + OFF_WVHI);
    __bf16* wvlo = (__bf16*)(ws + OFF_WVLO);
    __bf16* wohi = (__bf16*)(ws + OFF_WOHI);
    __bf16* wolo = (__bf16*)(ws + OFF_WOLO);
    __bf16* v2hi = (__bf16*)(ws + OFF_XHI);     // alias: X planes dead after GEMM1
    __bf16* v2lo = (__bf16*)(ws + OFF_XLO);
    float2* grev = (float2*)(ws + OFF_WVHI);    // alias: Wv planes dead after GEMM1

    hipMemsetAsync(ws + OFF_XSUM, 0, 4096 * sizeof(float), stream);
    k_tw<<<16, 256, 0, stream>>>(ws + OFF_TW);
    k_meansplit<<<dim3(64, 4), 256, 0, stream>>>(x, ws + OFF_XSUM, xhi, xlo);
    k_barhidden<<<64, 256, 0, stream>>>(ws + OFF_XSUM, Wq, ln_g, ln_b, Wgup, Wwup,
                                        ws + OFF_HG, ws + OFF_HW);
    k_gategemv<<<dim3(17, 8, 2), 256, 0, stream>>>(Wgdn, Wwdn, ws + OFF_HG, ws + OFF_HW,
                                                   ws + OFF_GATE, ws + OFF_S);
    k_coef<<<dim3(8, 64), 256, 0, stream>>>(ws + OFF_S, ws + OFF_CA, ws + OFF_CD);

    k_split<<<1024, 256, 0, stream>>>(Wv, wvhi, wvlo, CD * CD / 4);
    k_split<<<1024, 256, 0, stream>>>(Wo, wohi, wolo, CD * CD / 4);

    // GEMM1: Vcol[b*1024+d][n] = x @ Wv.T (transposed store)
    k_mfma_gemm<1><<<256, 512, 0, stream>>>(xhi, xlo, wvhi, wvlo, ws + OFF_VCOL);

    // build digit-reversed hermitian gate table (into dead Wv-hi region)
    k_grev<<<dim3(16, 64), 256, 0, stream>>>(ws + OFF_GATE, grev);

    k_fft<<<2048, 512, 0, stream>>>(ws + OFF_VCOL, grev, ws + OFF_CA, ws + OFF_CD,
                                    (const float2*)(ws + OFF_TW));

    // transpose+split v_t for GEMM2
    k_tsplit<<<dim3(128, 32, 4), 256, 0, stream>>>(ws + OFF_VCOL, v2hi, v2lo);

    // GEMM2: out[bn][d'] = v_t @ Wo.T (row-major store)
    k_mfma_gemm<0><<<256, 512, 0, stream>>>(v2hi, v2lo, wohi, wolo, out);
}

// Round 10
// 389.015 us; speedup vs baseline: 1.0847x; 1.0847x over previous
//
#include <hip/hip_runtime.h>

// ---------------- problem config ----------------
constexpr int CB = 4, CN = 4096, CD = 1024, CH = 16, CDH = 64, CGH = 256, CFREQ = 2049, CBH = 64;

// ---------------- workspace layout (float offsets) ----------------
constexpr size_t OFF_XSUM = 0;                                   // 4096
constexpr size_t OFF_HG   = 4096;
constexpr size_t OFF_HW   = OFF_HG + (size_t)CBH * CGH;
constexpr size_t OFF_GATE = OFF_HW + (size_t)CBH * CGH;
constexpr size_t OFF_S    = OFF_GATE + (size_t)CBH * 2 * CFREQ;
constexpr size_t OFF_CA   = OFF_S + (size_t)CBH * CN;
constexpr size_t OFF_CD   = OFF_CA + (size_t)CBH * (CN / 2);
constexpr size_t OFF_TW   = OFF_CD + (size_t)CBH * (CN / 2);     // 4096 float2 = 8192 floats
constexpr size_t OFF_VCOL = OFF_TW + 8192;                       // fp32 [b][d][n]
constexpr size_t OFF_XHI  = OFF_VCOL + (size_t)CB * CD * CN;     // bf16 planes
constexpr size_t OFF_XLO  = OFF_XHI + (size_t)CB * CN * CD / 2;
constexpr size_t OFF_WVHI = OFF_XLO + (size_t)CB * CN * CD / 2;
constexpr size_t OFF_WVLO = OFF_WVHI + (size_t)CD * CD / 2;
constexpr size_t OFF_WOHI = OFF_WVLO + (size_t)CD * CD / 2;
constexpr size_t OFF_WOLO = OFF_WOHI + (size_t)CD * CD / 2;
// V2 planes alias X planes (X dead after GEMM1).
// g~rev table (64 x 4096 float2) aliases WVHI (dead after GEMM1).

typedef __bf16 bf16x8 __attribute__((ext_vector_type(8)));
typedef __bf16 bf16x4 __attribute__((ext_vector_type(4)));
typedef float  f32x4  __attribute__((ext_vector_type(4)));
typedef float  f32x16 __attribute__((ext_vector_type(16)));

__device__ __forceinline__ float silu_f(float x) { return x / (1.0f + expf(-x)); }

__device__ __forceinline__ void gload16(const void* g, void* l) {
    __builtin_amdgcn_global_load_lds(
        reinterpret_cast<const __attribute__((address_space(1))) unsigned int*>(
            reinterpret_cast<uintptr_t>(g)),
        reinterpret_cast<__attribute__((address_space(3))) unsigned int*>(
            reinterpret_cast<uintptr_t>(l)),
        16, 0, 0);
}

// complex helpers
__device__ __forceinline__ float2 cadd(float2 a, float2 b) { return make_float2(a.x + b.x, a.y + b.y); }
__device__ __forceinline__ float2 csub(float2 a, float2 b) { return make_float2(a.x - b.x, a.y - b.y); }
__device__ __forceinline__ float2 cmul(float2 a, float2 b) { return make_float2(a.x * b.x - a.y * b.y, a.x * b.y + a.y * b.x); }
__device__ __forceinline__ float2 cmulc(float2 a, float2 b) { return make_float2(a.x * b.x + a.y * b.y, a.y * b.x - a.x * b.y); } // a*conj(b)
__device__ __forceinline__ float2 mulni(float2 a) { return make_float2(a.y, -a.x); }  // a * (-i)
__device__ __forceinline__ float2 mulpi(float2 a) { return make_float2(-a.y, a.x); }  // a * (+i)

// padded LDS slot: uniform bank residues for all stage strides
__device__ __forceinline__ int P(int r) { return r + (r >> 3); }

// base-8 digit reversal of 12-bit index (involution)
__device__ __forceinline__ int drev8(int k) {
    return ((k & 7) << 9) | (((k >> 3) & 7) << 6) | (((k >> 6) & 7) << 3) | ((k >> 9) & 7);
}

// 8-pt DFT, forward (w = e^{-2pi i/8})
__device__ __forceinline__ void dft8_fwd(const float2 a[8], float2 A[8]) {
    float2 t0 = cadd(a[0], a[4]), t1 = csub(a[0], a[4]);
    float2 t2 = cadd(a[2], a[6]), t3 = mulni(csub(a[2], a[6]));
    float2 t4 = cadd(a[1], a[5]), t5 = csub(a[1], a[5]);
    float2 t6 = cadd(a[3], a[7]), t7 = mulni(csub(a[3], a[7]));
    float2 u0 = cadd(t0, t2), u1 = csub(t0, t2);
    float2 u2 = cadd(t1, t3), u3 = csub(t1, t3);
    float2 u4 = cadd(t4, t6), u5 = mulni(csub(t4, t6));
    float2 u6 = cadd(t5, t7), u7 = csub(t5, t7);
    const float s = 0.70710678118654752f;
    float2 w6 = make_float2(s * (u6.x + u6.y), s * (u6.y - u6.x));
    float2 w7 = make_float2(s * (u7.y - u7.x), -s * (u7.x + u7.y));
    A[0] = cadd(u0, u4); A[4] = csub(u0, u4);
    A[2] = cadd(u1, u5); A[6] = csub(u1, u5);
    A[1] = cadd(u2, w6); A[5] = csub(u2, w6);
    A[3] = cadd(u3, w7); A[7] = csub(u3, w7);
}

// 8-pt DFT, inverse (w = e^{+2pi i/8})
__device__ __forceinline__ void dft8_inv(const float2 a[8], float2 A[8]) {
    float2 t0 = cadd(a[0], a[4]), t1 = csub(a[0], a[4]);
    float2 t2 = cadd(a[2], a[6]), t3 = mulpi(csub(a[2], a[6]));
    float2 t4 = cadd(a[1], a[5]), t5 = csub(a[1], a[5]);
    float2 t6 = cadd(a[3], a[7]), t7 = mulpi(csub(a[3], a[7]));
    float2 u0 = cadd(t0, t2), u1 = csub(t0, t2);
    float2 u2 = cadd(t1, t3), u3 = csub(t1, t3);
    float2 u4 = cadd(t4, t6), u5 = mulpi(csub(t4, t6));
    float2 u6 = cadd(t5, t7), u7 = csub(t5, t7);
    const float s = 0.70710678118654752f;
    float2 w6 = make_float2(s * (u6.x - u6.y), s * (u6.x + u6.y));
    float2 w7 = make_float2(-s * (u7.x + u7.y), s * (u7.x - u7.y));
    A[0] = cadd(u0, u4); A[4] = csub(u0, u4);
    A[2] = cadd(u1, u5); A[6] = csub(u1, u5);
    A[1] = cadd(u2, w6); A[5] = csub(u2, w6);
    A[3] = cadd(u3, w7); A[7] = csub(u3, w7);
}

template <int M>
__device__ __forceinline__ void fwd_stage(float2* buf, const float2* __restrict__ tw, int t) {
    int j = t & (M - 1);
    int i0 = ((t & ~(M - 1)) << 3) + j;
    constexpr int TS = 512 / M;
    float2 a[8], A[8];
#pragma unroll
    for (int c = 0; c < 8; ++c) a[c] = buf[P(i0 + c * M)];
    dft8_fwd(a, A);
#pragma unroll
    for (int p = 0; p < 8; ++p) {
        float2 v = (M > 1 && p) ? cmul(A[p], tw[j * p * TS]) : A[p];
        buf[P(i0 + p * M)] = v;
    }
}

template <int M>
__device__ __forceinline__ void inv_stage(float2* buf, const float2* __restrict__ tw, int t) {
    int j = t & (M - 1);
    int i0 = ((t & ~(M - 1)) << 3) + j;
    constexpr int TS = 512 / M;
    float2 a[8], A[8];
#pragma unroll
    for (int c = 0; c < 8; ++c) {
        float2 v = buf[P(i0 + c * M)];
        a[c] = (M > 1 && c) ? cmulc(v, tw[j * c * TS]) : v;
    }
    dft8_inv(a, A);
#pragma unroll
    for (int p = 0; p < 8; ++p) buf[P(i0 + p * M)] = A[p];
}

// ---------------- twiddle table ----------------
__global__ void k_tw(float* twf) {
    int i = blockIdx.x * 256 + threadIdx.x;
    if (i < 4096) {
        double ang = -2.0 * 3.14159265358979323846 * (double)i / 4096.0;
        twf[2 * i]     = (float)cos(ang);
        twf[2 * i + 1] = (float)sin(ang);
    }
}

// ---------------- g~ in digit-reversed order ----------------
__global__ __launch_bounds__(256) void k_grev(const float* __restrict__ gateB,
                                              float2* __restrict__ grev) {
    int bh = blockIdx.y;
    int r = blockIdx.x * 256 + threadIdx.x;   // 0..4095
    int k = drev8(r);
    const float2* g2 = (const float2*)gateB + (size_t)bh * CFREQ;
    float2 g;
    if (k <= 2048) g = g2[k];
    else { float2 gg = g2[4096 - k]; g = make_float2(gg.x, -gg.y); }
    grev[(size_t)bh * 4096 + r] = g;
}

// ---------------- column sums of x over N, fused with hi/lo bf16 split ----------------
__global__ __launch_bounds__(256) void k_meansplit(const float* __restrict__ X, float* __restrict__ xsum,
                                                   __bf16* __restrict__ hi, __bf16* __restrict__ lo) {
    int b = blockIdx.y;
    int c = blockIdx.x;
    int t = threadIdx.x;
    int half = t >> 7;
    int col = (t & 127) * 8;
    size_t base = (size_t)b * CN * CD + ((size_t)c * 64 + half * 32) * CD + col;
    float acc[8];
#pragma unroll
    for (int j = 0; j < 8; ++j) acc[j] = 0.f;
    for (int n = 0; n < 32; ++n) {
        size_t o = base + (size_t)n * CD;
        float4 v0 = *(const float4*)(X + o);
        float4 v1 = *(const float4*)(X + o + 4);
        float vv[8] = {v0.x, v0.y, v0.z, v0.w, v1.x, v1.y, v1.z, v1.w};
        bf16x8 hv, lv;
#pragma unroll
        for (int j = 0; j < 8; ++j) {
            acc[j] += vv[j];
            __bf16 h = (__bf16)vv[j];
            hv[j] = h;
            lv[j] = (__bf16)(vv[j] - (float)h);
        }
        *(bf16x8*)&hi[o] = hv;
        *(bf16x8*)&lo[o] = lv;
    }
#pragma unroll
    for (int j = 0; j < 8; ++j) atomicAdd(&xsum[b * CD + col + j], acc[j]);
}

// ---------------- bar = LN(mean_n q) ; hidden = silu(bar @ Wup.T) ----------------
__global__ __launch_bounds__(256) void k_barhidden(const float* __restrict__ xsum,
                                                   const float* __restrict__ Wq,
                                                   const float* __restrict__ ln_g,
                                                   const float* __restrict__ ln_b,
                                                   const float* __restrict__ Wgup,
                                                   const float* __restrict__ Wwup,
                                                   float* __restrict__ hg, float* __restrict__ hw) {
    int bh = blockIdx.x;
    int b = bh >> 4, h = bh & 15;
    int t = threadIdx.x;
    __shared__ float part[256];
    __shared__ float bar_s[64];
    int dh = t >> 2, seg = t & 3;
    const float* wrow = Wq + (size_t)(h * 64 + dh) * CD + seg * 256;
    const float* xs = xsum + b * CD + seg * 256;
    float acc = 0.f;
    for (int i = 0; i < 256; i += 4) {
        float4 w4 = *(const float4*)(wrow + i);
        float4 x4 = *(const float4*)(xs + i);
        acc += w4.x * x4.x + w4.y * x4.y + w4.z * x4.z + w4.w * x4.w;
    }
    part[t] = acc;
    __syncthreads();
    if (t < 64) {
        float q = (part[4 * t] + part[4 * t + 1] + part[4 * t + 2] + part[4 * t + 3]) * (1.0f / 4096.0f);
        float mu = q;
        for (int o = 32; o >= 1; o >>= 1) mu += __shfl_xor(mu, o, 64);
        mu *= (1.0f / 64.0f);
        float dev = q - mu;
        float vv = dev * dev;
        for (int o = 32; o >= 1; o >>= 1) vv += __shfl_xor(vv, o, 64);
        vv *= (1.0f / 64.0f);
        bar_s[t] = dev / sqrtf(vv + 1e-6f) * ln_g[t] + ln_b[t];
    }
    __syncthreads();
    const float* gup = Wgup + (size_t)t * CDH;
    const float* wup = Wwup + (size_t)t * CDH;
    float ag = 0.f, aw = 0.f;
    for (int i = 0; i < CDH; i += 4) {
        float4 bb = *(const float4*)(&bar_s[i]);
        float4 g4 = *(const float4*)(gup + i);
        float4 w4 = *(const float4*)(wup + i);
        ag += g4.x * bb.x + g4.y * bb.y + g4.z * bb.z + g4.w * bb.w;
        aw += w4.x * bb.x + w4.y * bb.y + w4.z * bb.z + w4.w * bb.w;
    }
    hg[bh * CGH + t] = silu_f(ag);
    hw[bh * CGH + t] = silu_f(aw);
}

// ---------------- gr / s GEMVs ----------------
__global__ __launch_bounds__(256) void k_gategemv(const float* __restrict__ Wgdn,
                                                  const float* __restrict__ Wwdn,
                                                  const float* __restrict__ hg,
                                                  const float* __restrict__ hw,
                                                  float* __restrict__ gate, float* __restrict__ sbuf) {
    int z = blockIdx.z;
    const float* Wd = z ? Wwdn : Wgdn;
    const float* hid = z ? hw : hg;
    float* out = z ? sbuf : gate;
    int Kout = z ? CN : 2 * CFREQ;
    int bh0 = blockIdx.y * 8;
    int t = threadIdx.x;
    int k = blockIdx.x * 256 + t;
    __shared__ float Lh[8][256];
    for (int g = 0; g < 8; ++g) Lh[g][t] = hid[(size_t)(bh0 + g) * CGH + t];
    __syncthreads();
    if (k >= Kout) return;
    float accv[8] = {0.f, 0.f, 0.f, 0.f, 0.f, 0.f, 0.f, 0.f};
    const float* wrow = Wd + (size_t)k * CGH;
    for (int j4 = 0; j4 < 64; ++j4) {
        float4 wv = *(const float4*)(wrow + 4 * j4);
#pragma unroll
        for (int g = 0; g < 8; ++g) {
            accv[g] += wv.x * Lh[g][4 * j4] + wv.y * Lh[g][4 * j4 + 1] +
                       wv.z * Lh[g][4 * j4 + 2] + wv.w * Lh[g][4 * j4 + 3];
        }
    }
    for (int g = 0; g < 8; ++g) out[(size_t)(bh0 + g) * Kout + k] = accv[g];
}

// ---------------- mixing coefficients ----------------
__global__ __launch_bounds__(256) void k_coef(const float* __restrict__ sbuf,
                                              float* __restrict__ ca, float* __restrict__ cd) {
    int bh = blockIdx.y;
    int i = blockIdx.x * 256 + threadIdx.x;
    float s0 = sbuf[(size_t)bh * CN + i];
    float s1 = sbuf[(size_t)bh * CN + 2048 + i];
    ca[(size_t)bh * 2048 + i] = 1.0f + 0.5f * (s0 + s1);
    cd[(size_t)bh * 2048 + i] = 0.5f * (s0 - s1);
}

// ---------------- fp32 -> (hi,lo) bf16 split (weights) ----------------
__global__ __launch_bounds__(256) void k_split(const float* __restrict__ src,
                                               __bf16* __restrict__ hi, __bf16* __restrict__ lo,
                                               int n4) {
    int i = blockIdx.x * 256 + threadIdx.x;
    int stride = gridDim.x * 256;
    for (; i < n4; i += stride) {
        float4 v = ((const float4*)src)[i];
        __bf16 h0 = (__bf16)v.x, h1 = (__bf16)v.y, h2 = (__bf16)v.z, h3 = (__bf16)v.w;
        bf16x4 hv = {h0, h1, h2, h3};
        bf16x4 lv = {(__bf16)(v.x - (float)h0), (__bf16)(v.y - (float)h1),
                     (__bf16)(v.z - (float)h2), (__bf16)(v.w - (float)h3)};
        *(bf16x4*)&hi[4 * (size_t)i] = hv;
        *(bf16x4*)&lo[4 * (size_t)i] = lv;
    }
}

// ---------------- transpose + split: Vcol fp32 [b][d][n] -> V2 planes [b*n][d] ----------------
__global__ __launch_bounds__(256) void k_tsplit(const float* __restrict__ Vcol,
                                                __bf16* __restrict__ hi, __bf16* __restrict__ lo) {
    __shared__ float tile[32][33];
    int bx = blockIdx.x;
    int by = blockIdx.y;
    int b  = blockIdx.z;
    int t = threadIdx.x;
    int d = t >> 3, n4 = (t & 7) * 4;
    const float* src = Vcol + ((size_t)b * CD + by * 32 + d) * CN + bx * 32 + n4;
    float4 v = *(const float4*)src;
    tile[d][n4] = v.x; tile[d][n4 + 1] = v.y; tile[d][n4 + 2] = v.z; tile[d][n4 + 3] = v.w;
    __syncthreads();
    int n = t >> 3, d4 = (t & 7) * 4;
    size_t o = ((size_t)b * CN + bx * 32 + n) * CD + by * 32 + d4;
    float x0 = tile[d4][n], x1 = tile[d4 + 1][n], x2 = tile[d4 + 2][n], x3 = tile[d4 + 3][n];
    __bf16 h0 = (__bf16)x0, h1 = (__bf16)x1, h2 = (__bf16)x2, h3 = (__bf16)x3;
    bf16x4 hv = {h0, h1, h2, h3};
    bf16x4 lv = {(__bf16)(x0 - (float)h0), (__bf16)(x1 - (float)h1),
                 (__bf16)(x2 - (float)h2), (__bf16)(x3 - (float)h3)};
    *(bf16x4*)&hi[o] = hv;
    *(bf16x4*)&lo[o] = lv;
}

// ---------------- split-bf16 MFMA GEMM: 256x256 tile, 8 waves, 4-phase schedule ----------------
template <int TRANS>
__global__ __launch_bounds__(512, 2) void k_mfma_gemm(const __bf16* __restrict__ Ahi,
                                                      const __bf16* __restrict__ Alo,
                                                      const __bf16* __restrict__ Bhi,
                                                      const __bf16* __restrict__ Blo,
                                                      float* __restrict__ C) {
    __shared__ __align__(16) __bf16 lds[2][4][256 * 32];   // 128 KB
    int t = threadIdx.x;
    int l = t & 63, w = t >> 6;          // 8 waves
    int wm = w >> 2, wn = w & 3;         // 2m x 4n
    int hw = blockIdx.x;
    int xcd = hw & 7, slot = hw >> 3;    // 32 blocks per XCD: 8m x 4n
    int m0 = (xcd * 8 + (slot >> 2)) * 256;
    int n0 = (slot & 3) * 256;

    int pl = w >> 1;
    const __bf16* gsrc = (pl == 0) ? Ahi : (pl == 1) ? Alo : (pl == 2) ? Bhi : Blo;
    int gr0 = (pl < 2) ? m0 : n0;
    unsigned o[8];
    int rl0[8];
#pragma unroll
    for (int i = 0; i < 8; ++i) {
        int rl = (w & 1) * 128 + i * 16 + (l >> 2);
        unsigned sq = (unsigned)((l & 3) ^ ((rl >> 2) & 3));
        o[i] = (unsigned)(gr0 + rl) * 1024u + sq * 8u;
        rl0[i] = (w & 1) * 128 + i * 16;
    }

    f32x16 acc[4][2];
#pragma unroll
    for (int mi = 0; mi < 4; ++mi)
#pragma unroll
        for (int ni = 0; ni < 2; ++ni)
#pragma unroll
            for (int q = 0; q < 16; ++q) acc[mi][ni][q] = 0.f;

#pragma unroll
    for (int i = 0; i < 8; ++i)
        gload16(gsrc + (size_t)o[i], &lds[0][pl][rl0[i] * 32]);
    __syncthreads();

#pragma unroll 1
    for (int t32 = 0; t32 < 32; ++t32) {
        int cur = t32 & 1;
        size_t koff = (size_t)(t32 + 1) * 32;
        bool pf = (t32 + 1) < 32;
        bf16x8 bfr[2][2][2];
#pragma unroll
        for (int p = 0; p < 4; ++p) {
            if (pf) {
                gload16(gsrc + ((size_t)o[2 * p] + koff), &lds[cur ^ 1][pl][rl0[2 * p] * 32]);
                gload16(gsrc + ((size_t)o[2 * p + 1] + koff), &lds[cur ^ 1][pl][rl0[2 * p + 1] * 32]);
            }
            bf16x8 afr[2][2];
            int arow = wm * 128 + p * 32 + (l & 31);
            int akey = (arow >> 2) & 3;
#pragma unroll
            for (int s = 0; s < 2; ++s) {
                int sl = ((l >> 5) + 2 * s) ^ akey;
                afr[s][0] = *(const bf16x8*)&lds[cur][0][arow * 32 + sl * 8];
                afr[s][1] = *(const bf16x8*)&lds[cur][1][arow * 32 + sl * 8];
            }
            if (p == 0) {
#pragma unroll
                for (int ni = 0; ni < 2; ++ni) {
                    int bcol = wn * 64 + ni * 32 + (l & 31);
                    int bkey = (bcol >> 2) & 3;
#pragma unroll
                    for (int s = 0; s < 2; ++s) {
                        int sl = ((l >> 5) + 2 * s) ^ bkey;
                        bfr[ni][s][0] = *(const bf16x8*)&lds[cur][2][bcol * 32 + sl * 8];
                        bfr[ni][s][1] = *(const bf16x8*)&lds[cur][3][bcol * 32 + sl * 8];
                    }
                }
            }
            __builtin_amdgcn_s_barrier();
            __builtin_amdgcn_s_setprio(1);
#pragma unroll
            for (int ni = 0; ni < 2; ++ni)
#pragma unroll
                for (int s = 0; s < 2; ++s) {
                    acc[p][ni] = __builtin_amdgcn_mfma_f32_32x32x16_bf16(afr[s][0], bfr[ni][s][0], acc[p][ni], 0, 0, 0);
                    acc[p][ni] = __builtin_amdgcn_mfma_f32_32x32x16_bf16(afr[s][0], bfr[ni][s][1], acc[p][ni], 0, 0, 0);
                    acc[p][ni] = __builtin_amdgcn_mfma_f32_32x32x16_bf16(afr[s][1], bfr[ni][s][0], acc[p][ni], 0, 0, 0);
                }
            __builtin_amdgcn_s_setprio(0);
            __builtin_amdgcn_s_barrier();
        }
        __syncthreads();
    }

    if (TRANS) {
        int b = m0 >> 12;
        int tokb = (m0 & 4095) + wm * 128;
#pragma unroll
        for (int mi = 0; mi < 4; ++mi)
#pragma unroll
            for (int ni = 0; ni < 2; ++ni) {
                int dcol = n0 + wn * 64 + ni * 32 + (l & 31);
                float* base = C + ((size_t)(b * CD + dcol)) * CN;
#pragma unroll
                for (int q = 0; q < 4; ++q) {
                    int tok = tokb + mi * 32 + 8 * q + 4 * (l >> 5);
                    f32x4 v = {acc[mi][ni][4 * q], acc[mi][ni][4 * q + 1],
                               acc[mi][ni][4 * q + 2], acc[mi][ni][4 * q + 3]};
                    *(f32x4*)&base[tok] = v;
                }
            }
    } else {
#pragma unroll
        for (int mi = 0; mi < 4; ++mi)
#pragma unroll
            for (int ni = 0; ni < 2; ++ni) {
                int cc = n0 + wn * 64 + ni * 32 + (l & 31);
#pragma unroll
                for (int q = 0; q < 4; ++q) {
                    int r0 = m0 + wm * 128 + mi * 32 + 8 * q + 4 * (l >> 5);
#pragma unroll
                    for (int j = 0; j < 4; ++j)
                        C[(size_t)(r0 + j) * CD + cc] = acc[mi][ni][4 * q + j];
                }
            }
    }
}

// ---------------- FFT chain: radix-8 in registers, fused pointwise gate, 6 barriers ----------------
// NOTE: launch_bounds (512,2) — round 9's (512,8) forced a 64-VGPR cap and spilled to
// scratch (WRITE_SIZE 64->241 MB). 256-VGPR budget: no spill; occupancy from actual count.
__global__ __launch_bounds__(512, 2) void k_fft(float* __restrict__ Vcol,
                                                const float2* __restrict__ grevB,
                                                const float* __restrict__ caB,
                                                const float* __restrict__ cdB,
                                                const float2* __restrict__ tw) {
    __shared__ float2 buf[4608];   // 4096 + pad(r>>3), 36 KB
    int blk = blockIdx.x;
    int bh = blk >> 5, pr = blk & 31;
    int t = threadIdx.x;
    float* colA = Vcol + (size_t)(bh * 64 + pr * 2) * CN;
    float* colB = colA + CN;

    // fwd stage M=512: global -> regs -> dft8 -> twiddle -> LDS
    {
        float2 a[8], A[8];
#pragma unroll
        for (int c = 0; c < 8; ++c) {
            int n = t + 512 * c;
            a[c] = make_float2(colA[n], colB[n]);
        }
        dft8_fwd(a, A);
#pragma unroll
        for (int p = 0; p < 8; ++p) {
            float2 v = p ? cmul(A[p], tw[t * p]) : A[p];
            buf[P(t + 512 * p)] = v;
        }
    }
    __syncthreads();
    fwd_stage<64>(buf, tw, t);  __syncthreads();
    fwd_stage<8>(buf, tw, t);   __syncthreads();

    // fused: fwd stage M=1 + pointwise gate (W[r] = g~rev[r] * Z[r]) + inv stage M=1
    {
        const float2* gr = grevB + (size_t)bh * 4096 + (t << 3);
        int i0 = t << 3;
        float2 a[8], A[8];
#pragma unroll
        for (int c = 0; c < 8; ++c) a[c] = buf[P(i0 + c)];
        dft8_fwd(a, A);
#pragma unroll
        for (int p = 0; p < 8; ++p) A[p] = cmul(gr[p], A[p]);
        dft8_inv(A, a);
#pragma unroll
        for (int p = 0; p < 8; ++p) buf[P(i0 + p)] = a[p];
    }
    __syncthreads();

    inv_stage<8>(buf, tw, t);   __syncthreads();
    inv_stage<64>(buf, tw, t);  __syncthreads();

    // inv stage M=512 in registers + shfl-pair epilogue
    {
        float2 a[8], A[8];
#pragma unroll
        for (int c = 0; c < 8; ++c) {
            float2 v = buf[P(t + 512 * c)];
            a[c] = c ? cmulc(v, tw[t * c]) : v;
        }
        dft8_inv(a, A);
        const float scale = 1.0f / 4096.0f;
        const float* ca = caB + (size_t)bh * 2048;
        const float* cd = cdB + (size_t)bh * 2048;
#pragma unroll
        for (int p = 0; p < 8; ++p) {
            int n = t + 512 * p;
            int i = n >> 1;
            float A_ = ca[i] * scale, D_ = cd[i] * scale;
            float ox = __shfl_xor(A[p].x, 1, 64);
            float oy = __shfl_xor(A[p].y, 1, 64);
            colA[n] = A_ * A[p].x + D_ * ox;
            colB[n] = A_ * A[p].y + D_ * oy;
        }
    }
}

// ---------------- launch ----------------
extern "C" void kernel_launch(void* const* d_in, const int* in_sizes, int n_in,
                              void* d_out, int out_size, void* d_ws, size_t ws_size,
                              hipStream_t stream) {
    const float* x    = (const float*)d_in[0];
    const float* Wq   = (const float*)d_in[1];
    const float* Wv   = (const float*)d_in[2];
    const float* Wo   = (const float*)d_in[3];
    const float* ln_g = (const float*)d_in[4];
    const float* ln_b = (const float*)d_in[5];
    const float* Wgup = (const float*)d_in[6];
    const float* Wgdn = (const float*)d_in[7];
    const float* Wwup = (const float*)d_in[8];
    const float* Wwdn = (const float*)d_in[9];
    float* ws  = (float*)d_ws;
    float* out = (float*)d_out;

    __bf16* xhi  = (__bf16*)(ws + OFF_XHI);
    __bf16* xlo  = (__bf16*)(ws + OFF_XLO);
    __bf16* wvhi = (__bf16*)(ws + OFF_WVHI);
    __bf16* wvlo = (__bf16*)(ws + OFF_WVLO);
    __bf16* wohi = (__bf16*)(ws + OFF_WOHI);
    __bf16* wolo = (__bf16*)(ws + OFF_WOLO);
    __bf16* v2hi = (__bf16*)(ws + OFF_XHI);     // alias: X planes dead after GEMM1
    __bf16* v2lo = (__bf16*)(ws + OFF_XLO);
    float2* grev = (float2*)(ws + OFF_WVHI);    // alias: Wv planes dead after GEMM1

    hipMemsetAsync(ws + OFF_XSUM, 0, 4096 * sizeof(float), stream);
    k_tw<<<16, 256, 0, stream>>>(ws + OFF_TW);
    k_meansplit<<<dim3(64, 4), 256, 0, stream>>>(x, ws + OFF_XSUM, xhi, xlo);
    k_barhidden<<<64, 256, 0, stream>>>(ws + OFF_XSUM, Wq, ln_g, ln_b, Wgup, Wwup,
                                        ws + OFF_HG, ws + OFF_HW);
    k_gategemv<<<dim3(17, 8, 2), 256, 0, stream>>>(Wgdn, Wwdn, ws + OFF_HG, ws + OFF_HW,
                                                   ws + OFF_GATE, ws + OFF_S);
    k_coef<<<dim3(8, 64), 256, 0, stream>>>(ws + OFF_S, ws + OFF_CA, ws + OFF_CD);

    k_split<<<1024, 256, 0, stream>>>(Wv, wvhi, wvlo, CD * CD / 4);
    k_split<<<1024, 256, 0, stream>>>(Wo, wohi, wolo, CD * CD / 4);

    // GEMM1: Vcol[b*1024+d][n] = x @ Wv.T (transposed store)
    k_mfma_gemm<1><<<256, 512, 0, stream>>>(xhi, xlo, wvhi, wvlo, ws + OFF_VCOL);

    // build digit-reversed hermitian gate table (into dead Wv-hi region)
    k_grev<<<dim3(16, 64), 256, 0, stream>>>(ws + OFF_GATE, grev);

    k_fft<<<2048, 512, 0, stream>>>(ws + OFF_VCOL, grev, ws + OFF_CA, ws + OFF_CD,
                                    (const float2*)(ws + OFF_TW));

    // transpose+split v_t for GEMM2
    k_tsplit<<<dim3(128, 32, 4), 256, 0, stream>>>(ws + OFF_VCOL, v2hi, v2lo);

    // GEMM2: out[bn][d'] = v_t @ Wo.T (row-major store)
    k_mfma_gemm<0><<<256, 512, 0, stream>>>(v2hi, v2lo, wohi, wolo, out);
}